// Round 2
// baseline (6088.347 us; speedup 1.0000x reference)
//
#include <hip/hip_runtime.h>
#include <stdint.h>

typedef unsigned long long u64;
typedef unsigned int u32;

#define NPTS    131072
#define NBATCH  16
#define NSAMP   1024
#define THREADS 256
#define WPB     64                 // waves per batch: 16 blocks * 4 waves
#define PPT     32                 // points per thread
#define WCHUNK  2048               // points per wave

// Packed candidate word: [ tag:10 (bits 49..58) | key:32 (17..48) | (131071-idx):17 (0..16) ]
// key = 0 for masked-out (cand == -1), else float_bits(val)+1 (monotone for val >= 0).
// Max of packed (same tag) == reference first-max argmax (smaller index wins ties).

__global__ __launch_bounds__(THREADS, 1)
void fps_kernel(const float* __restrict__ x, float* __restrict__ y, u64* __restrict__ slots)
{
    const int bid   = blockIdx.x;
    const int batch = bid & (NBATCH - 1);   // consecutive bids round-robin XCDs
    const int sub   = bid >> 4;
    const int tid   = threadIdx.x;
    const int lane  = tid & 63;
    const int wv    = tid >> 6;
    const int wslot = sub * 4 + wv;         // 0..63 within batch

    const float* __restrict__ xb = x + (size_t)batch * (NPTS * 3);
    const int gbase = sub * 8192 + wv * WCHUNK;

    // register-resident points + running min distance (static indexing only)
    float px_[PPT], py_[PPT], pz_[PPT], t_[PPT];

#pragma unroll
    for (int k = 0; k < PPT; ++k) {
        const int g = gbase + k * 64 + lane;
        const float a = xb[3 * g + 0];
        const float b = xb[3 * g + 1];
        const float c = xb[3 * g + 2];
        px_[k] = a; py_[k] = b; pz_[k] = c;
        // exactly as reference: ((a*a + b*b) + c*c), no FMA contraction
        const float mag = __fadd_rn(__fadd_rn(__fmul_rn(a, a), __fmul_rn(b, b)), __fmul_rn(c, c));
        t_[k] = (mag > 1e-3f) ? 1e10f : -1.0f;   // masked-out: cand == -1 forever
    }

    float cpx = xb[0], cpy = xb[1], cpz = xb[2];   // first pick is always index 0
    const bool writer = (wslot == 0 && lane == 0);
    if (writer) {
        float* yo = y + (size_t)batch * (NSAMP * 3);
        yo[0] = cpx; yo[1] = cpy; yo[2] = cpz;
    }

    u64* const sb0 = slots + (size_t)batch * WPB;             // parity 0
    u64* const sb1 = slots + (size_t)(NBATCH + batch) * WPB;  // parity 1

    for (int it = 1; it < NSAMP; ++it) {
        // ---- update temps against current point, thread-local argmax ----
        float bv = -2.0f;
        int   bk = 0;
#pragma unroll
        for (int k = 0; k < PPT; ++k) {
            const float dx = __fsub_rn(px_[k], cpx);
            const float dy = __fsub_rn(py_[k], cpy);
            const float dz = __fsub_rn(pz_[k], cpz);
            const float d  = __fadd_rn(__fadd_rn(__fmul_rn(dx, dx), __fmul_rn(dy, dy)),
                                       __fmul_rn(dz, dz));
            const float tn = fminf(t_[k], d);
            t_[k] = tn;
            if (tn > bv) { bv = tn; bk = k; }   // strict > keeps smallest k
        }
        const int gidx = gbase + bk * 64 + lane;
        const u32 key  = (bv < 0.0f) ? 0u : (__float_as_uint(bv) + 1u);
        u64 packed = ((u64)(u32)it << 49) | ((u64)key << 17) | (u32)(131071 - gidx);

        // ---- wave reduce (max of packed, first-max tiebreak) ----
#pragma unroll
        for (int off = 32; off; off >>= 1) {
            const u64 o = __shfl_xor(packed, off);
            if (o > packed) packed = o;
        }

        u64* const sb = (it & 1) ? sb1 : sb0;
        if (lane == 0)
            __hip_atomic_store(sb + wslot, packed, __ATOMIC_RELAXED, __HIP_MEMORY_SCOPE_AGENT);

        // ---- each lane polls one of the 64 sibling slots for this round's tag ----
        u64 v;
        {
            u64* const sp = sb + lane;
            do {
                v = __hip_atomic_load(sp, __ATOMIC_RELAXED, __HIP_MEMORY_SCOPE_AGENT);
            } while ((u32)(v >> 49) != (u32)it);
        }
        // ---- wave reduce over the 64 slot values ----
#pragma unroll
        for (int off = 32; off; off >>= 1) {
            const u64 o = __shfl_xor(v, off);
            if (o > v) v = o;
        }

        const int widx = 131071 - (int)(v & 0x1FFFF);
        cpx = xb[3 * widx + 0];   // x is read-only -> caches safe; chunk is L2-resident
        cpy = xb[3 * widx + 1];
        cpz = xb[3 * widx + 2];
        if (writer) {
            float* yo = y + ((size_t)batch * NSAMP + it) * 3;
            yo[0] = cpx; yo[1] = cpy; yo[2] = cpz;
        }
    }
}

extern "C" void kernel_launch(void* const* d_in, const int* in_sizes, int n_in,
                              void* d_out, int out_size, void* d_ws, size_t ws_size,
                              hipStream_t stream) {
    const float* x = (const float*)d_in[0];
    float* y       = (float*)d_out;
    u64* slots     = (u64*)d_ws;   // 2 * 16 * 64 * 8 = 16 KiB

    // zero slot tags so no stale tag can match (tags used are 1..1023)
    hipMemsetAsync(d_ws, 0, (size_t)(2 * NBATCH * WPB * sizeof(u64)), stream);

    void* args[] = { (void*)&x, (void*)&y, (void*)&slots };
    hipLaunchCooperativeKernel((void*)fps_kernel,
                               dim3(NBATCH * 16), dim3(THREADS),
                               args, 0, stream);
}

// Round 5
// 2683.258 us; speedup vs baseline: 2.2690x; 2.2690x over previous
//
#include <hip/hip_runtime.h>
#include <stdint.h>

typedef unsigned long long u64;
typedef unsigned int u32;

#define NPTS    131072
#define NBATCH  16
#define NSAMP   1024
#define SUBS    16                 // blocks per batch
#define THREADS 256
#define PPT     32                 // points per thread

// Slot words, all relaxed agent-scope, all self-validating:
//   meta : [ tag:10 (bits 49..58) | key:32 (17..48) | (131071-idx):17 (0..16) ]
//          key = 0 for masked-out (cand == -1), else float_bits(val)+1.
//          Max of meta (same tag) == reference first-max argmax.
//   coord: [ it:32 (hi) | float_bits:32 (lo) ]  -- x,y,z of the block's candidate.
// Per-batch layout in ws (128 u64 = 1024B, exact):  base[par*64 + kind*16 + sub],
// kind: 0=meta 1=x 2=y 3=z. Each word written once per round by one lane; readers
// poll until their word's own tag matches -> no inter-word ordering needed.

__device__ __forceinline__ u64 ld_agent(const u64* p) {
    return __hip_atomic_load(p, __ATOMIC_RELAXED, __HIP_MEMORY_SCOPE_AGENT);
}
__device__ __forceinline__ void st_agent(u64* p, u64 v) {
    __hip_atomic_store(p, v, __ATOMIC_RELAXED, __HIP_MEMORY_SCOPE_AGENT);
}

__global__ __launch_bounds__(THREADS, 1)
void fps_kernel(const float* __restrict__ x, float* __restrict__ y, u64* __restrict__ ws)
{
    const int bid   = blockIdx.x;
    const int batch = bid & (NBATCH - 1);
    const int sub   = bid >> 4;
    const int tid   = threadIdx.x;
    const int lane  = tid & 63;
    const int wv    = tid >> 6;

    const float* __restrict__ xb = x + (size_t)batch * (NPTS * 3);
    const int gbase = sub * 8192 + wv * 2048;

    // register-resident points + running min distance (static indexing only)
    float px_[PPT], py_[PPT], pz_[PPT], t_[PPT];
#pragma unroll
    for (int k = 0; k < PPT; ++k) {
        const int g = gbase + k * 64 + lane;
        const float a = xb[3 * g + 0];
        const float b = xb[3 * g + 1];
        const float c = xb[3 * g + 2];
        px_[k] = a; py_[k] = b; pz_[k] = c;
        // exactly as reference: ((a*a + b*b) + c*c), no FMA contraction
        const float mag = __fadd_rn(__fadd_rn(__fmul_rn(a, a), __fmul_rn(b, b)), __fmul_rn(c, c));
        t_[k] = (mag > 1e-3f) ? 1e10f : -1.0f;   // masked-out: cand == -1 forever
    }

    // ---- bisect probe: execute s_getreg(HW_REG_XCC_ID), keep live, use nothing ----
    {
        u32 xcc = (u32)__builtin_amdgcn_s_getreg((31 << 11) | 20);
        asm volatile("" :: "s"(xcc));
    }

    __shared__ u64   s_red[2][4][4];   // [parity][wave][meta, xword, yword, zword]
    __shared__ float s_p[3];

    u64* const base = ws + (size_t)batch * 128;   // 1024B per batch

    float cpx = xb[0], cpy = xb[1], cpz = xb[2];   // first pick is always index 0
    if (sub == 0 && tid == 0) {
        float* yo = y + (size_t)batch * (NSAMP * 3);
        yo[0] = cpx; yo[1] = cpy; yo[2] = cpz;
    }

    for (int it = 1; it < NSAMP; ++it) {
        // ---- update temps against current point; track best value, index, coords ----
        float bv = -2.0f, bx = 0.0f, by = 0.0f, bz = 0.0f;
        int   bk = 0;
#pragma unroll
        for (int k = 0; k < PPT; ++k) {
            const float dx = __fsub_rn(px_[k], cpx);
            const float dy = __fsub_rn(py_[k], cpy);
            const float dz = __fsub_rn(pz_[k], cpz);
            const float d  = __fadd_rn(__fadd_rn(__fmul_rn(dx, dx), __fmul_rn(dy, dy)),
                                       __fmul_rn(dz, dz));
            const float tn = fminf(t_[k], d);
            t_[k] = tn;
            if (tn > bv) { bv = tn; bk = k; bx = px_[k]; by = py_[k]; bz = pz_[k]; }
        }
        const int gidx = gbase + bk * 64 + lane;
        const u32 key  = (bv < 0.0f) ? 0u : (__float_as_uint(bv) + 1u);
        const u64 mine = ((u64)(u32)it << 49) | ((u64)key << 17) | (u32)(131071 - gidx);
        u64 packed = mine;

        // ---- wave reduce (max of packed; unique low bits -> unique winner) ----
#pragma unroll
        for (int off = 32; off; off >>= 1) {
            const u64 o = __shfl_xor(packed, off);
            if (o > packed) packed = o;
        }

        const int par  = it & 1;
        const u64 ctag = (u64)(u32)it << 32;
        if (packed == mine) {                      // exactly one lane per wave
            s_red[par][wv][1] = ctag | __float_as_uint(bx);
            s_red[par][wv][2] = ctag | __float_as_uint(by);
            s_red[par][wv][3] = ctag | __float_as_uint(bz);
        }
        if (lane == 0) s_red[par][wv][0] = packed;  // parity-buffered (no overwrite race)
        __syncthreads();

        if (wv == 0) {
            if (lane == 0) {
                // combine 4 wave candidates, publish meta + winner's coords
                u64 blk = s_red[par][0][0]; int w = 0;
                if (s_red[par][1][0] > blk) { blk = s_red[par][1][0]; w = 1; }
                if (s_red[par][2][0] > blk) { blk = s_red[par][2][0]; w = 2; }
                if (s_red[par][3][0] > blk) { blk = s_red[par][3][0]; w = 3; }
                u64* sp = base + par * 64;
                st_agent(sp + sub,      blk);
                st_agent(sp + 16 + sub, s_red[par][w][1]);
                st_agent(sp + 32 + sub, s_red[par][w][2]);
                st_agent(sp + 48 + sub, s_red[par][w][3]);
            }
            // ---- poll: 64 lanes cover {meta,x,y,z} x 16 subs, each self-validated ----
            const int kind = lane >> 4;
            const u64* sp  = base + par * 64 + lane;   // kind*16 + (lane&15) == lane
            u64 v;
            for (;;) {
                v = ld_agent(sp);
                const bool fresh = kind ? ((u32)(v >> 32) == (u32)it)
                                        : ((u32)(v >> 49) == (u32)it);
                if (__all((int)fresh)) break;
            }
            const u64 m0 = v;
            // reduce meta within 16-lane groups (offsets 8..1 stay in-group;
            // lanes 16+ reduce coord words -> garbage, unused)
#pragma unroll
            for (int off = 8; off; off >>= 1) {
                const u64 o = __shfl_xor(v, off);
                if (o > v) v = o;
            }
            const u64 win  = __shfl(v, 0);
            const int widx = 131071 - (int)(win & 0x1FFFF);
            const int wblk = widx >> 13;               // owning block (8192-pt chunks)
            const u64 xw = __shfl(m0, 16 + wblk);
            const u64 yw = __shfl(m0, 32 + wblk);
            const u64 zw = __shfl(m0, 48 + wblk);
            if (lane == 0) {
                const float wx = __uint_as_float((u32)xw);
                const float wy = __uint_as_float((u32)yw);
                const float wz = __uint_as_float((u32)zw);
                s_p[0] = wx; s_p[1] = wy; s_p[2] = wz;
                if (sub == 0) {
                    float* yo = y + ((size_t)batch * NSAMP + it) * 3;
                    yo[0] = wx; yo[1] = wy; yo[2] = wz;
                }
            }
        }
        __syncthreads();
        cpx = s_p[0]; cpy = s_p[1]; cpz = s_p[2];
    }
}

extern "C" void kernel_launch(void* const* d_in, const int* in_sizes, int n_in,
                              void* d_out, int out_size, void* d_ws, size_t ws_size,
                              hipStream_t stream) {
    const float* x = (const float*)d_in[0];
    float* y       = (float*)d_out;
    u64* ws        = (u64*)d_ws;   // 16 batches * 1024B = 16 KiB

    // zero all slot words; tags used are 1..1023, so zeroed/stale/poisoned lines
    // can never spuriously satisfy a round's tag check (memset replays in-graph)
    hipMemsetAsync(d_ws, 0, (size_t)(NBATCH * 1024), stream);

    void* args[] = { (void*)&x, (void*)&y, (void*)&ws };
    hipLaunchCooperativeKernel((void*)fps_kernel,
                               dim3(NBATCH * SUBS), dim3(THREADS),
                               args, 0, stream);
}

// Round 6
// 2025.697 us; speedup vs baseline: 3.0056x; 1.3246x over previous
//
#include <hip/hip_runtime.h>
#include <stdint.h>

typedef unsigned long long u64;
typedef unsigned int u32;

#define NPTS    131072
#define NBATCH  16
#define NSAMP   1024
#define SUBS    16                 // blocks per batch
#define THREADS 256
#define PPT     32                 // points per thread
#define DET_TAG 1023u              // agent parity-0 slots only see even tags 2..1022 from the main loop
#define CAP     64                 // fast polls before PERMANENT fallback to the agent line

// Packed word: [ tag:10 (bits 49..58) | key:32 (17..48) | (131071-idx):17 (0..16) ]
// key = 0 for masked-out (cand == -1), else float_bits(val)+1 (monotone for val >= 0).
// Max of packed (same tag) == reference first-max argmax (smaller index wins ties).
//
// Per-batch ws layout (1024B stride; batches never share cache lines):
//   +0    fast  slots: parity p at +p*16 u64, slot sub. RMW-only (exec at local XCD TCC).
//   +512  agent slots: same shape. LLC path: XCD detection + fallback target.

__device__ __forceinline__ u64 ld_agent(const u64* p) {
    return __hip_atomic_load(p, __ATOMIC_RELAXED, __HIP_MEMORY_SCOPE_AGENT);
}
__device__ __forceinline__ void st_agent(u64* p, u64 v) {
    __hip_atomic_store(p, v, __ATOMIC_RELAXED, __HIP_MEMORY_SCOPE_AGENT);
}
// Atomic RMWs execute at the issuing XCD's TCC (L2): no L1 staleness, ~3-4x lower
// latency than the LLC. Only meaningful when all communicating blocks share the
// XCD -- verified at runtime below; never trusted for correctness (CAP fallback).
__device__ __forceinline__ void pub_fast(u64* p, u64 v) {
    (void)__hip_atomic_exchange(p, v, __ATOMIC_RELAXED, __HIP_MEMORY_SCOPE_WORKGROUP);
}
__device__ __forceinline__ u64 poll_fast(u64* p) {
    return __hip_atomic_fetch_add(p, 0ull, __ATOMIC_RELAXED, __HIP_MEMORY_SCOPE_WORKGROUP);
}

__global__ __launch_bounds__(THREADS, 1)
void fps_kernel(const float* __restrict__ x, float* __restrict__ y, u64* __restrict__ ws)
{
    const int bid   = blockIdx.x;
    const int batch = bid & (NBATCH - 1);   // under round-robin dispatch: all 16 blocks on XCD bid%8
    const int sub   = bid >> 4;
    const int tid   = threadIdx.x;
    const int lane  = tid & 63;
    const int wv    = tid >> 6;

    const float* __restrict__ xb = x + (size_t)batch * (NPTS * 3);
    const int gbase = sub * 8192 + wv * 2048;

    // register-resident points + running min distance (static indexing only)
    float px_[PPT], py_[PPT], pz_[PPT], t_[PPT];
#pragma unroll
    for (int k = 0; k < PPT; ++k) {
        const int g = gbase + k * 64 + lane;
        const float a = xb[3 * g + 0];
        const float b = xb[3 * g + 1];
        const float c = xb[3 * g + 2];
        px_[k] = a; py_[k] = b; pz_[k] = c;
        // exactly as reference: ((a*a + b*b) + c*c), no FMA contraction
        const float mag = __fadd_rn(__fadd_rn(__fmul_rn(a, a), __fmul_rn(b, b)), __fmul_rn(c, c));
        t_[k] = (mag > 1e-3f) ? 1e10f : -1.0f;   // masked-out: cand == -1 forever
    }

    __shared__ u64   s_red[2][4];
    __shared__ float s_p[3];

    u64* const fastS  = ws + (size_t)batch * 128;   // 1024B per batch (u64 units)
    u64* const agentS = fastS + 64;                 // +512B

    // ---- detect same-XCD batch via the proven agent path (s_getreg exonerated in r5) ----
    const u32 xcc = (u32)__builtin_amdgcn_s_getreg((31 << 11) | 20) & 0xFu;  // HW_REG_XCC_ID
    if (tid == 0) st_agent(agentS + sub, ((u64)DET_TAG << 49) | xcc);
    u64 dv;
    {
        const u64* sp = agentS + (lane & 15);
        do { dv = ld_agent(sp); } while ((u32)(dv >> 49) != DET_TAG);
    }
    const bool fast = __all((int)(dv == __shfl(dv, 0)));

    float cpx = xb[0], cpy = xb[1], cpz = xb[2];   // first pick is always index 0
    if (sub == 0 && tid == 0) {
        float* yo = y + (size_t)batch * (NSAMP * 3);
        yo[0] = cpx; yo[1] = cpy; yo[2] = cpz;
    }

    bool agent_only = false;   // sticky fallback (wave0 uniform)

    for (int it = 1; it < NSAMP; ++it) {
        // ---- update temps against current point, thread-local argmax ----
        float bv = -2.0f;
        int   bk = 0;
#pragma unroll
        for (int k = 0; k < PPT; ++k) {
            const float dx = __fsub_rn(px_[k], cpx);
            const float dy = __fsub_rn(py_[k], cpy);
            const float dz = __fsub_rn(pz_[k], cpz);
            const float d  = __fadd_rn(__fadd_rn(__fmul_rn(dx, dx), __fmul_rn(dy, dy)),
                                       __fmul_rn(dz, dz));
            const float tn = fminf(t_[k], d);
            t_[k] = tn;
            if (tn > bv) { bv = tn; bk = k; }   // strict > keeps smallest k
        }
        const int gidx = gbase + bk * 64 + lane;
        const u32 key  = (bv < 0.0f) ? 0u : (__float_as_uint(bv) + 1u);
        u64 packed = ((u64)(u32)it << 49) | ((u64)key << 17) | (u32)(131071 - gidx);

        // ---- wave reduce (max of packed, first-max tiebreak) ----
#pragma unroll
        for (int off = 32; off; off >>= 1) {
            const u64 o = __shfl_xor(packed, off);
            if (o > packed) packed = o;
        }

        const int par = it & 1;
        if (lane == 0) s_red[par][wv] = packed;   // parity-buffered: no cross-round overwrite
        __syncthreads();

        if (wv == 0) {
            if (lane == 0) {
                u64 blk = s_red[par][0];
                if (s_red[par][1] > blk) blk = s_red[par][1];
                if (s_red[par][2] > blk) blk = s_red[par][2];
                if (s_red[par][3] > blk) blk = s_red[par][3];
                if (fast) pub_fast(fastS + par * SUBS + sub, blk);  // local-XCD L2 line
                st_agent(agentS + par * SUBS + sub, blk);           // fallback line, always
            }
            // ---- poll the 16 slots (lanes 0..15 only; one RMW per slot per try) ----
            u64* const spF = fastS  + par * SUBS + lane;
            u64* const spA = agentS + par * SUBS + lane;
            u64 v = 0;
            int tries = 0;
            for (;;) {
                bool fresh = true;
                if (lane < 16) {
                    v = (fast && !agent_only) ? poll_fast(spF) : ld_agent(spA);
                    fresh = ((u32)(v >> 49) == (u32)it);
                }
                if (__all((int)fresh)) break;
                if (fast && !agent_only && ++tries >= CAP) agent_only = true;
            }
            // reduce the 16 slot values (offsets 8..1 stay within lanes 0..15)
#pragma unroll
            for (int off = 8; off; off >>= 1) {
                const u64 o = __shfl_xor(v, off);
                if (o > v) v = o;
            }
            if (lane == 0) {
                const int widx = 131071 - (int)(v & 0x1FFFF);
                const float wx = xb[3 * widx + 0];   // read-only input: cache-safe
                const float wy = xb[3 * widx + 1];
                const float wz = xb[3 * widx + 2];
                s_p[0] = wx; s_p[1] = wy; s_p[2] = wz;
                if (sub == 0) {
                    float* yo = y + ((size_t)batch * NSAMP + it) * 3;
                    yo[0] = wx; yo[1] = wy; yo[2] = wz;
                }
            }
        }
        __syncthreads();
        cpx = s_p[0]; cpy = s_p[1]; cpz = s_p[2];
    }
}

extern "C" void kernel_launch(void* const* d_in, const int* in_sizes, int n_in,
                              void* d_out, int out_size, void* d_ws, size_t ws_size,
                              hipStream_t stream) {
    const float* x = (const float*)d_in[0];
    float* y       = (float*)d_out;
    u64* ws        = (u64*)d_ws;   // 16 batches * 1024B = 16 KiB

    // zero all slot words every call (in-graph). Tags used are 1..1023; stale
    // content (zeros, 0xAA poison, or a previous replay's final tags) can never
    // spuriously satisfy a round's tag check -- see lineage argument in comments.
    hipMemsetAsync(d_ws, 0, (size_t)(NBATCH * 1024), stream);

    void* args[] = { (void*)&x, (void*)&y, (void*)&ws };
    hipLaunchCooperativeKernel((void*)fps_kernel,
                               dim3(NBATCH * SUBS), dim3(THREADS),
                               args, 0, stream);
}